// Round 1
// baseline (4159.180 us; speedup 1.0000x reference)
//
#include <hip/hip_runtime.h>
#include <stdint.h>

// HistMatching: out[b,i] = t_sorted[rank of x[b,i] within sample b]
// rank = stable order (value asc, original index asc) -> sort composite (u32key, idx).
// Bucket-count approach: 22-bit bucket histogram + scan + bucketed scatter of
// (key,idx) u64 pairs + per-element pairwise rank within small bucket.

#define SEG_N 2621440            // 1*128*160*128, per sample / template
#define K_BITS 22
#define NB (1u << K_BITS)        // 4,194,304 buckets
#define KSHIFT (32 - K_BITS)     // 10
#define SCAN_CHUNK 4096          // per block in scan kernels (256 thr x 16)

// monotone f32 -> u32 (order-preserving)
__device__ __forceinline__ uint32_t fkey(float f) {
  uint32_t b = __float_as_uint(f);
  return b ^ ((b & 0x80000000u) ? 0xFFFFFFFFu : 0x80000000u);
}
__device__ __forceinline__ float finv(uint32_t u) {
  uint32_t b = u ^ ((u & 0x80000000u) ? 0x80000000u : 0xFFFFFFFFu);
  return __uint_as_float(b);
}

// ---------------- histogram ----------------
__global__ __launch_bounds__(256) void histo_k(const float* __restrict__ x,
                                               uint32_t* __restrict__ cnt) {
  uint32_t i = (blockIdx.x * 256u + threadIdx.x) * 4u;
  const float4 v = *reinterpret_cast<const float4*>(x + i);
  atomicAdd(&cnt[fkey(v.x) >> KSHIFT], 1u);
  atomicAdd(&cnt[fkey(v.y) >> KSHIFT], 1u);
  atomicAdd(&cnt[fkey(v.z) >> KSHIFT], 1u);
  atomicAdd(&cnt[fkey(v.w) >> KSHIFT], 1u);
}

// ---------------- exclusive scan over NB counters (3 kernels) ----------------
__device__ __forceinline__ uint32_t block_excl_scan_256(uint32_t v, uint32_t* lds) {
  const int t = threadIdx.x;
  lds[t] = v;
  __syncthreads();
#pragma unroll
  for (int off = 1; off < 256; off <<= 1) {
    uint32_t a = (t >= off) ? lds[t - off] : 0u;
    __syncthreads();
    lds[t] += a;
    __syncthreads();
  }
  uint32_t ex = (t == 0) ? 0u : lds[t - 1];
  __syncthreads();
  return ex;
}

__global__ __launch_bounds__(256) void scan_a_k(const uint32_t* __restrict__ cnt,
                                                uint32_t* __restrict__ partials) {
  __shared__ uint32_t lds[256];
  const int t = threadIdx.x;
  size_t base = (size_t)blockIdx.x * SCAN_CHUNK + (size_t)t * 16;
  const uint4* p = reinterpret_cast<const uint4*>(cnt + base);
  uint32_t s = 0;
#pragma unroll
  for (int k = 0; k < 4; ++k) {
    uint4 a = p[k];
    s += a.x + a.y + a.z + a.w;
  }
  lds[t] = s;
  __syncthreads();
  for (int off = 128; off > 0; off >>= 1) {
    if (t < off) lds[t] += lds[t + off];
    __syncthreads();
  }
  if (t == 0) partials[blockIdx.x] = lds[0];
}

__global__ __launch_bounds__(256) void scan_b_k(uint32_t* __restrict__ partials) {
  // 1024 partials, 256 threads x 4 each -> exclusive scan in place
  __shared__ uint32_t lds[256];
  const int t = threadIdx.x;
  uint4 v = reinterpret_cast<uint4*>(partials)[t];
  uint32_t s = v.x + v.y + v.z + v.w;
  uint32_t ex = block_excl_scan_256(s, lds);
  uint4 o;
  o.x = ex;
  o.y = o.x + v.x;
  o.z = o.y + v.y;
  o.w = o.z + v.z;
  reinterpret_cast<uint4*>(partials)[t] = o;
}

__global__ __launch_bounds__(256) void scan_c_k(uint32_t* __restrict__ cnt,
                                                const uint32_t* __restrict__ partials) {
  __shared__ uint32_t lds[256];
  const int t = threadIdx.x;
  size_t base = (size_t)blockIdx.x * SCAN_CHUNK + (size_t)t * 16;
  uint4* p = reinterpret_cast<uint4*>(cnt + base);
  uint4 a[4];
  uint32_t s = 0;
#pragma unroll
  for (int k = 0; k < 4; ++k) {
    a[k] = p[k];
    s += a[k].x + a[k].y + a[k].z + a[k].w;
  }
  uint32_t ex = block_excl_scan_256(s, lds);
  uint32_t run = partials[blockIdx.x] + ex;
#pragma unroll
  for (int k = 0; k < 4; ++k) {
    uint4 o;
    o.x = run; run += a[k].x;
    o.y = run; run += a[k].y;
    o.z = run; run += a[k].z;
    o.w = run; run += a[k].w;
    p[k] = o;
  }
}

// ---------------- bucketed scatter of (key,idx) pairs ----------------
__global__ __launch_bounds__(256) void scatter_k(const float* __restrict__ x,
                                                 uint32_t* __restrict__ cursor,
                                                 uint64_t* __restrict__ pairs) {
  uint32_t i = blockIdx.x * 256u + threadIdx.x;
  uint32_t u = fkey(x[i]);
  uint32_t b = u >> KSHIFT;
  uint32_t pos = atomicAdd(&cursor[b], 1u);
  pairs[pos] = ((uint64_t)u << 32) | (uint64_t)i;
}

// ---------------- rank via pairwise count within bucket, then emit ----------------
// After scatter, cursor[b] = inclusive CDF; bucket b extent = [cursor[b-1], cursor[b])
__global__ __launch_bounds__(256) void rank_tmpl_k(const uint64_t* __restrict__ pairs,
                                                   const uint32_t* __restrict__ cdf,
                                                   float* __restrict__ tsorted) {
  uint32_t j = blockIdx.x * 256u + threadIdx.x;
  uint64_t mine = pairs[j];
  uint32_t b = (uint32_t)(mine >> (32 + KSHIFT));
  uint32_t start = b ? cdf[b - 1] : 0u;
  uint32_t end = cdf[b];
  uint32_t local = 0;
  for (uint32_t t = start; t < end; ++t) local += (pairs[t] < mine) ? 1u : 0u;
  tsorted[start + local] = finv((uint32_t)(mine >> 32));
}

__global__ __launch_bounds__(256) void rank_out_k(const uint64_t* __restrict__ pairs,
                                                  const uint32_t* __restrict__ cdf,
                                                  const float* __restrict__ tsorted,
                                                  float* __restrict__ out) {
  uint32_t j = blockIdx.x * 256u + threadIdx.x;
  uint64_t mine = pairs[j];
  uint32_t b = (uint32_t)(mine >> (32 + KSHIFT));
  uint32_t start = b ? cdf[b - 1] : 0u;
  uint32_t end = cdf[b];
  uint32_t local = 0;
  for (uint32_t t = start; t < end; ++t) local += (pairs[t] < mine) ? 1u : 0u;
  out[(uint32_t)mine] = tsorted[start + local];
}

extern "C" void kernel_launch(void* const* d_in, const int* in_sizes, int n_in,
                              void* d_out, int out_size, void* d_ws, size_t ws_size,
                              hipStream_t stream) {
  const float* x = (const float*)d_in[0];      // (8,1,128,160,128) f32
  const float* tmpl = (const float*)d_in[1];   // (1,128,160,128)  f32
  float* out = (float*)d_out;

  uint8_t* ws = (uint8_t*)d_ws;
  uint32_t* cursor = (uint32_t*)ws;                                   // NB u32   = 16.78 MB
  uint64_t* pairs = (uint64_t*)(ws + (size_t)NB * 4);                 // SEG_N u64 = 20.97 MB
  float* tsorted = (float*)(ws + (size_t)NB * 4 + (size_t)SEG_N * 8); // SEG_N f32 = 10.49 MB
  uint32_t* partials = (uint32_t*)(ws + (size_t)NB * 4 + (size_t)SEG_N * 8 +
                                   (size_t)SEG_N * 4);                // NB/4096 u32

  for (int seg = 0; seg < 9; ++seg) {
    const float* src = (seg == 0) ? tmpl : (x + (size_t)(seg - 1) * SEG_N);
    hipMemsetAsync(cursor, 0, (size_t)NB * 4, stream);
    histo_k<<<SEG_N / 1024, 256, 0, stream>>>(src, cursor);
    scan_a_k<<<NB / SCAN_CHUNK, 256, 0, stream>>>(cursor, partials);
    scan_b_k<<<1, 256, 0, stream>>>(partials);
    scan_c_k<<<NB / SCAN_CHUNK, 256, 0, stream>>>(cursor, partials);
    scatter_k<<<SEG_N / 256, 256, 0, stream>>>(src, cursor, pairs);
    if (seg == 0) {
      rank_tmpl_k<<<SEG_N / 256, 256, 0, stream>>>(pairs, cursor, tsorted);
    } else {
      rank_out_k<<<SEG_N / 256, 256, 0, stream>>>(pairs, cursor, tsorted,
                                                  out + (size_t)(seg - 1) * SEG_N);
    }
  }
}

// Round 2
// 3498.480 us; speedup vs baseline: 1.1889x; 1.1889x over previous
//
#include <hip/hip_runtime.h>
#include <stdint.h>

// HistMatching: out[b,i] = t_sorted[rank of x[b,i] within sample b]
// rank = stable order (value asc, original index asc) -> sort composite (u32key, idx).
// Bucket-count approach: 22-bit bucket histogram + scan + bucketed scatter of
// (key,idx) u64 pairs + per-element pairwise rank within small bucket.
//
// R1 change: histogram & scatter are phased over 16 fixed key ranges (standard
// normal quantiles) so the atomic/write working set stays L2-resident --
// kills the 8x write amplification seen in R0 (WRITE_SIZE 165MB -> ~40MB).

#define SEG_N 2621440            // 1*128*160*128, per sample / template
#define K_BITS 22
#define NB (1u << K_BITS)        // 4,194,304 buckets
#define KSHIFT (32 - K_BITS)     // 10
#define SCAN_CHUNK 4096          // per block in scan kernels (256 thr x 16)
#define PASSES 16
#define BPP (SEG_N / 4096)       // 640 blocks per pass (4096 elems/block)

// monotone f32 -> u32 (order-preserving)
__device__ __forceinline__ uint32_t fkey(float f) {
  uint32_t b = __float_as_uint(f);
  return b ^ ((b & 0x80000000u) ? 0xFFFFFFFFu : 0x80000000u);
}
__device__ __forceinline__ float finv(uint32_t u) {
  uint32_t b = u ^ ((u & 0x80000000u) ? 0x80000000u : 0xFFFFFFFFu);
  return __uint_as_float(b);
}

// standard-normal quantiles at i/16, i=1..15 (perf heuristic only)
__constant__ float TH[PASSES - 1] = {
  -1.534121f, -1.150349f, -0.887147f, -0.674490f, -0.488776f, -0.318639f,
  -0.157311f, 0.0f, 0.157311f, 0.318639f, 0.488776f, 0.674490f, 0.887147f,
  1.150349f, 1.534121f};

__device__ __forceinline__ void pass_range(uint32_t pass, uint32_t& lob,
                                           uint32_t& hib) {
  lob = (pass == 0) ? 0u : (fkey(TH[pass - 1]) >> KSHIFT);
  hib = (pass == PASSES - 1) ? NB : (fkey(TH[pass]) >> KSHIFT);
}

// ---------------- histogram (phased) ----------------
__global__ __launch_bounds__(256) void histo_k(const float* __restrict__ x,
                                               uint32_t* __restrict__ cnt) {
  uint32_t pass = blockIdx.x / BPP;
  uint32_t blk = blockIdx.x % BPP;
  uint32_t lob, hib;
  pass_range(pass, lob, hib);
  const float4* p4 =
      reinterpret_cast<const float4*>(x) + (size_t)blk * 1024 + threadIdx.x;
  float4 v[4];
#pragma unroll
  for (int k = 0; k < 4; ++k) v[k] = p4[k * 256];
#pragma unroll
  for (int k = 0; k < 4; ++k) {
    float f[4] = {v[k].x, v[k].y, v[k].z, v[k].w};
#pragma unroll
    for (int c = 0; c < 4; ++c) {
      uint32_t b = fkey(f[c]) >> KSHIFT;
      if (b >= lob && b < hib) atomicAdd(&cnt[b], 1u);
    }
  }
}

// ---------------- exclusive scan over NB counters (3 kernels) ----------------
__device__ __forceinline__ uint32_t block_excl_scan_256(uint32_t v, uint32_t* lds) {
  const int t = threadIdx.x;
  lds[t] = v;
  __syncthreads();
#pragma unroll
  for (int off = 1; off < 256; off <<= 1) {
    uint32_t a = (t >= off) ? lds[t - off] : 0u;
    __syncthreads();
    lds[t] += a;
    __syncthreads();
  }
  uint32_t ex = (t == 0) ? 0u : lds[t - 1];
  __syncthreads();
  return ex;
}

__global__ __launch_bounds__(256) void scan_a_k(const uint32_t* __restrict__ cnt,
                                                uint32_t* __restrict__ partials) {
  __shared__ uint32_t lds[256];
  const int t = threadIdx.x;
  size_t base = (size_t)blockIdx.x * SCAN_CHUNK + (size_t)t * 16;
  const uint4* p = reinterpret_cast<const uint4*>(cnt + base);
  uint32_t s = 0;
#pragma unroll
  for (int k = 0; k < 4; ++k) {
    uint4 a = p[k];
    s += a.x + a.y + a.z + a.w;
  }
  lds[t] = s;
  __syncthreads();
  for (int off = 128; off > 0; off >>= 1) {
    if (t < off) lds[t] += lds[t + off];
    __syncthreads();
  }
  if (t == 0) partials[blockIdx.x] = lds[0];
}

__global__ __launch_bounds__(256) void scan_b_k(uint32_t* __restrict__ partials) {
  // 1024 partials, 256 threads x 4 each -> exclusive scan in place
  __shared__ uint32_t lds[256];
  const int t = threadIdx.x;
  uint4 v = reinterpret_cast<uint4*>(partials)[t];
  uint32_t s = v.x + v.y + v.z + v.w;
  uint32_t ex = block_excl_scan_256(s, lds);
  uint4 o;
  o.x = ex;
  o.y = o.x + v.x;
  o.z = o.y + v.y;
  o.w = o.z + v.z;
  reinterpret_cast<uint4*>(partials)[t] = o;
}

__global__ __launch_bounds__(256) void scan_c_k(uint32_t* __restrict__ cnt,
                                                const uint32_t* __restrict__ partials) {
  __shared__ uint32_t lds[256];
  const int t = threadIdx.x;
  size_t base = (size_t)blockIdx.x * SCAN_CHUNK + (size_t)t * 16;
  uint4* p = reinterpret_cast<uint4*>(cnt + base);
  uint4 a[4];
  uint32_t s = 0;
#pragma unroll
  for (int k = 0; k < 4; ++k) {
    a[k] = p[k];
    s += a[k].x + a[k].y + a[k].z + a[k].w;
  }
  uint32_t ex = block_excl_scan_256(s, lds);
  uint32_t run = partials[blockIdx.x] + ex;
#pragma unroll
  for (int k = 0; k < 4; ++k) {
    uint4 o;
    o.x = run; run += a[k].x;
    o.y = run; run += a[k].y;
    o.z = run; run += a[k].z;
    o.w = run; run += a[k].w;
    p[k] = o;
  }
}

// ---------------- bucketed scatter of (key,idx) pairs (phased) ----------------
__global__ __launch_bounds__(256) void scatter_k(const float* __restrict__ x,
                                                 uint32_t* __restrict__ cursor,
                                                 uint64_t* __restrict__ pairs) {
  uint32_t pass = blockIdx.x / BPP;
  uint32_t blk = blockIdx.x % BPP;
  uint32_t lob, hib;
  pass_range(pass, lob, hib);
  const float4* p4 =
      reinterpret_cast<const float4*>(x) + (size_t)blk * 1024 + threadIdx.x;
  float4 v[4];
#pragma unroll
  for (int k = 0; k < 4; ++k) v[k] = p4[k * 256];
#pragma unroll
  for (int k = 0; k < 4; ++k) {
    uint32_t i0 = (blk * 1024u + k * 256u + threadIdx.x) * 4u;
    float f[4] = {v[k].x, v[k].y, v[k].z, v[k].w};
#pragma unroll
    for (int c = 0; c < 4; ++c) {
      uint32_t u = fkey(f[c]);
      uint32_t b = u >> KSHIFT;
      if (b >= lob && b < hib) {
        uint32_t pos = atomicAdd(&cursor[b], 1u);
        pairs[pos] = ((uint64_t)u << 32) | (uint64_t)(i0 + c);
      }
    }
  }
}

// ---------------- rank via pairwise count within bucket, then emit ----------------
// After scatter, cursor[b] = inclusive CDF; bucket b extent = [cursor[b-1], cursor[b])
__global__ __launch_bounds__(256) void rank_tmpl_k(const uint64_t* __restrict__ pairs,
                                                   const uint32_t* __restrict__ cdf,
                                                   float* __restrict__ tsorted) {
  uint32_t j = blockIdx.x * 256u + threadIdx.x;
  uint64_t mine = pairs[j];
  uint32_t b = (uint32_t)(mine >> (32 + KSHIFT));
  uint32_t start = b ? cdf[b - 1] : 0u;
  uint32_t end = cdf[b];
  uint32_t local = 0;
  for (uint32_t t = start; t < end; ++t) local += (pairs[t] < mine) ? 1u : 0u;
  tsorted[start + local] = finv((uint32_t)(mine >> 32));
}

__global__ __launch_bounds__(256) void rank_out_k(const uint64_t* __restrict__ pairs,
                                                  const uint32_t* __restrict__ cdf,
                                                  const float* __restrict__ tsorted,
                                                  float* __restrict__ out) {
  uint32_t j = blockIdx.x * 256u + threadIdx.x;
  uint64_t mine = pairs[j];
  uint32_t b = (uint32_t)(mine >> (32 + KSHIFT));
  uint32_t start = b ? cdf[b - 1] : 0u;
  uint32_t end = cdf[b];
  uint32_t local = 0;
  for (uint32_t t = start; t < end; ++t) local += (pairs[t] < mine) ? 1u : 0u;
  out[(uint32_t)mine] = tsorted[start + local];
}

extern "C" void kernel_launch(void* const* d_in, const int* in_sizes, int n_in,
                              void* d_out, int out_size, void* d_ws, size_t ws_size,
                              hipStream_t stream) {
  const float* x = (const float*)d_in[0];      // (8,1,128,160,128) f32
  const float* tmpl = (const float*)d_in[1];   // (1,128,160,128)  f32
  float* out = (float*)d_out;

  uint8_t* ws = (uint8_t*)d_ws;
  uint32_t* cursor = (uint32_t*)ws;                                   // NB u32   = 16.78 MB
  uint64_t* pairs = (uint64_t*)(ws + (size_t)NB * 4);                 // SEG_N u64 = 20.97 MB
  float* tsorted = (float*)(ws + (size_t)NB * 4 + (size_t)SEG_N * 8); // SEG_N f32 = 10.49 MB
  uint32_t* partials = (uint32_t*)(ws + (size_t)NB * 4 + (size_t)SEG_N * 8 +
                                   (size_t)SEG_N * 4);                // NB/4096 u32

  for (int seg = 0; seg < 9; ++seg) {
    const float* src = (seg == 0) ? tmpl : (x + (size_t)(seg - 1) * SEG_N);
    hipMemsetAsync(cursor, 0, (size_t)NB * 4, stream);
    histo_k<<<PASSES * BPP, 256, 0, stream>>>(src, cursor);
    scan_a_k<<<NB / SCAN_CHUNK, 256, 0, stream>>>(cursor, partials);
    scan_b_k<<<1, 256, 0, stream>>>(partials);
    scan_c_k<<<NB / SCAN_CHUNK, 256, 0, stream>>>(cursor, partials);
    scatter_k<<<PASSES * BPP, 256, 0, stream>>>(src, cursor, pairs);
    if (seg == 0) {
      rank_tmpl_k<<<SEG_N / 256, 256, 0, stream>>>(pairs, cursor, tsorted);
    } else {
      rank_out_k<<<SEG_N / 256, 256, 0, stream>>>(pairs, cursor, tsorted,
                                                  out + (size_t)(seg - 1) * SEG_N);
    }
  }
}

// Round 3
// 1269.077 us; speedup vs baseline: 3.2773x; 2.7567x over previous
//
#include <hip/hip_runtime.h>
#include <stdint.h>

// HistMatching via stable LSD radix sort (4 x 8-bit passes) of (key32,idx32)
// u64 pairs per segment. Stability via per-(bin,block) histogram matrix +
// exclusive scan (no per-element global atomics). Final pass fuses the
// epilogue: template -> tsorted[dest]=val; samples -> out[idx]=tsorted[dest].

#define SEG_N 2621440            // 128*160*128
#define NSEG 9                   // template + 8 samples
#define TILE 4096
#define NBLK (SEG_N / TILE)      // 640 blocks per segment
#define RADIX 256
#define HL (RADIX * NBLK)        // 163840 histogram-matrix entries per seg
#define SCHUNK 4096
#define SNB (HL / SCHUNK)        // 40 scan blocks per seg
#define SBUF (TILE + (TILE >> 4))  // 4352 u64, padded 1-per-16

// monotone f32 -> u32 (order-preserving)
__device__ __forceinline__ uint32_t fkey(float f) {
  uint32_t b = __float_as_uint(f);
  return b ^ ((b & 0x80000000u) ? 0xFFFFFFFFu : 0x80000000u);
}
__device__ __forceinline__ float finv(uint32_t u) {
  uint32_t b = u ^ ((u & 0x80000000u) ? 0x80000000u : 0xFFFFFFFFu);
  return __uint_as_float(b);
}
__device__ __forceinline__ uint32_t SIDX(uint32_t i) { return i + (i >> 4); }

// ---------- init: build pairsA in index order + digit-0 histogram ----------
__global__ __launch_bounds__(256) void init_k(const float* __restrict__ x,
                                              const float* __restrict__ tmpl,
                                              int segbase,
                                              uint64_t* __restrict__ pairsA,
                                              uint32_t* __restrict__ Hkb) {
  __shared__ uint32_t hist[RADIX];
  const int t = threadIdx.x;
  const int blk = blockIdx.x;
  const int sl = blockIdx.y;
  const int seg = segbase + sl;
  const float* src = (seg == 0) ? tmpl : (x + (size_t)(seg - 1) * SEG_N);
  uint64_t* pa = pairsA + (size_t)sl * SEG_N;
  hist[t] = 0;
  __syncthreads();
  const uint32_t base = blk * TILE;
  const float4* s4 = reinterpret_cast<const float4*>(src + base);
#pragma unroll
  for (int r = 0; r < 4; ++r) {
    float4 v = s4[r * 256 + t];
    uint32_t i0 = base + (uint32_t)(r * 256 + t) * 4u;
    float f[4] = {v.x, v.y, v.z, v.w};
#pragma unroll
    for (int c = 0; c < 4; ++c) {
      uint32_t k = fkey(f[c]);
      atomicAdd(&hist[k & 255u], 1u);
      pa[i0 + c] = ((uint64_t)k << 32) | (uint64_t)(i0 + c);
    }
  }
  __syncthreads();
  Hkb[(size_t)sl * HL + (size_t)blk * RADIX + t] = hist[t];  // [blk][bin]
}

// ---------- histogram of digit p over current pairs ----------
__global__ __launch_bounds__(256) void hist_k(const uint64_t* __restrict__ pairs,
                                              uint32_t* __restrict__ Hkb, int p) {
  __shared__ uint32_t hist[RADIX];
  const int t = threadIdx.x;
  const int blk = blockIdx.x;
  const int sl = blockIdx.y;
  const uint64_t* pc = pairs + (size_t)sl * SEG_N + (size_t)blk * TILE;
  hist[t] = 0;
  __syncthreads();
  const int sh = 32 + 8 * p;
#pragma unroll
  for (int r = 0; r < 16; ++r) {
    uint64_t e = pc[r * 256 + t];
    atomicAdd(&hist[(uint32_t)(e >> sh) & 255u], 1u);
  }
  __syncthreads();
  Hkb[(size_t)sl * HL + (size_t)blk * RADIX + t] = hist[t];
}

// ---------- transpose [blk][bin] -> [bin][blk] (scan-order) ----------
__global__ __launch_bounds__(256) void transp_k(const uint32_t* __restrict__ Hkb,
                                                uint32_t* __restrict__ Hbk) {
  __shared__ uint32_t tile[64][65];
  const int sl = blockIdx.y;
  const uint32_t* src = Hkb + (size_t)sl * HL;
  uint32_t* dst = Hbk + (size_t)sl * HL;
  const int kt = blockIdx.x % (NBLK / 64);  // 10 k-tiles
  const int bt = blockIdx.x / (NBLK / 64);  // 4 b-tiles
  const int tx = threadIdx.x & 63, ty = threadIdx.x >> 6;
#pragma unroll
  for (int r = 0; r < 16; ++r) {
    int k = kt * 64 + ty + r * 4;
    tile[ty + r * 4][tx] = src[(size_t)k * RADIX + bt * 64 + tx];
  }
  __syncthreads();
#pragma unroll
  for (int r = 0; r < 16; ++r) {
    int b = bt * 64 + ty + r * 4;
    dst[(size_t)b * NBLK + kt * 64 + tx] = tile[tx][ty + r * 4];
  }
}

// ---------- 3-level exclusive scan over Hbk (length HL per seg) ----------
__device__ __forceinline__ uint32_t block_excl_scan_256(uint32_t v, uint32_t* lds) {
  const int t = threadIdx.x;
  lds[t] = v;
  __syncthreads();
#pragma unroll
  for (int off = 1; off < 256; off <<= 1) {
    uint32_t a = (t >= off) ? lds[t - off] : 0u;
    __syncthreads();
    lds[t] += a;
    __syncthreads();
  }
  uint32_t ex = (t == 0) ? 0u : lds[t - 1];
  __syncthreads();
  return ex;
}

__global__ __launch_bounds__(256) void scan_a_k(const uint32_t* __restrict__ Hbk,
                                                uint32_t* __restrict__ partials) {
  __shared__ uint32_t lds[256];
  const int t = threadIdx.x;
  const uint32_t* c = Hbk + (size_t)blockIdx.y * HL +
                      (size_t)blockIdx.x * SCHUNK + (size_t)t * 16;
  const uint4* p = reinterpret_cast<const uint4*>(c);
  uint32_t s = 0;
#pragma unroll
  for (int k = 0; k < 4; ++k) { uint4 a = p[k]; s += a.x + a.y + a.z + a.w; }
  lds[t] = s;
  __syncthreads();
  for (int off = 128; off > 0; off >>= 1) {
    if (t < off) lds[t] += lds[t + off];
    __syncthreads();
  }
  if (t == 0) partials[blockIdx.y * 64 + blockIdx.x] = lds[0];
}

__global__ __launch_bounds__(256) void scan_b_k(uint32_t* __restrict__ partials) {
  __shared__ uint32_t lds[256];
  const int t = threadIdx.x;
  uint32_t* p = partials + blockIdx.y * 64;
  uint32_t v = (t < SNB) ? p[t] : 0u;
  uint32_t ex = block_excl_scan_256(v, lds);
  if (t < SNB) p[t] = ex;
}

__global__ __launch_bounds__(256) void scan_c_k(uint32_t* __restrict__ Hbk,
                                                const uint32_t* __restrict__ partials) {
  __shared__ uint32_t lds[256];
  const int t = threadIdx.x;
  uint32_t* c = Hbk + (size_t)blockIdx.y * HL +
                (size_t)blockIdx.x * SCHUNK + (size_t)t * 16;
  uint4* p = reinterpret_cast<uint4*>(c);
  uint4 a[4];
  uint32_t s = 0;
#pragma unroll
  for (int k = 0; k < 4; ++k) {
    a[k] = p[k];
    s += a[k].x + a[k].y + a[k].z + a[k].w;
  }
  uint32_t ex = block_excl_scan_256(s, lds);
  uint32_t run = partials[blockIdx.y * 64 + blockIdx.x] + ex;
#pragma unroll
  for (int k = 0; k < 4; ++k) {
    uint4 o;
    o.x = run; run += a[k].x;
    o.y = run; run += a[k].y;
    o.z = run; run += a[k].z;
    o.w = run; run += a[k].w;
    p[k] = o;
  }
}

// ---------- dual packed-u16 exclusive scan over 256 threads ----------
__device__ __forceinline__ void scan_pack2(uint32_t v0, uint32_t v1, uint32_t* s,
                                           uint32_t& ex0, uint32_t& ex1,
                                           uint32_t& tot0, uint32_t& tot1) {
  const int lane = threadIdx.x & 63, w = threadIdx.x >> 6;
  uint32_t a = v0, b = v1;
#pragma unroll
  for (int o = 1; o < 64; o <<= 1) {
    uint32_t na = __shfl_up(a, (unsigned)o, 64);
    uint32_t nb = __shfl_up(b, (unsigned)o, 64);
    if (lane >= o) { a += na; b += nb; }
  }
  if (lane == 63) { s[w] = a; s[4 + w] = b; }
  __syncthreads();
  if (threadIdx.x == 0) {
    uint32_t r0 = 0, r1 = 0;
#pragma unroll
    for (int i = 0; i < 4; ++i) {
      uint32_t q0 = s[i], q1 = s[4 + i];
      s[i] = r0; s[4 + i] = r1;
      r0 += q0; r1 += q1;
    }
    s[8] = r0; s[9] = r1;
  }
  __syncthreads();
  ex0 = a - v0 + s[w];
  ex1 = b - v1 + s[4 + w];
  tot0 = s[8]; tot1 = s[9];
  __syncthreads();  // protect scratch before next-round reuse
}

// ---------- stable partition pass (templated digit P, output MODE) ----------
// MODE 0: write pairs to dst; MODE 1: tsorted[dest]=val; MODE 2: out[idx]=tsorted[dest]
template <int P, int MODE>
__global__ __launch_bounds__(256) void part_k(const uint64_t* __restrict__ src,
                                              uint64_t* __restrict__ dst,
                                              const uint32_t* __restrict__ Hbk,
                                              float* __restrict__ tsorted,
                                              float* __restrict__ out,
                                              int segbase, int slbase) {
  __shared__ uint64_t bufA[SBUF];
  __shared__ uint64_t bufB[SBUF];
  __shared__ uint32_t ldsHist[RADIX];
  __shared__ uint32_t ldsStart[RADIX];
  __shared__ uint32_t ldsBase[RADIX];
  __shared__ uint32_t scanS[12];
  const int t = threadIdx.x;
  const int blk = blockIdx.x;
  const int sl = slbase + blockIdx.y;
  const int seg = segbase + sl;
  const uint64_t* ps = src + (size_t)sl * SEG_N + (size_t)blk * TILE;

  // stage tile into LDS (coalesced), padded layout
#pragma unroll
  for (int r = 0; r < 16; ++r) bufA[SIDX(r * 256 + t)] = ps[r * 256 + t];
  __syncthreads();

  // 4 stable 2-bit split rounds (LSB-first within the byte): A->B->A->B->A
  uint64_t e[16];
  uint64_t* cur = bufA;
  uint64_t* nxt = bufB;
#pragma unroll
  for (int rnd = 0; rnd < 4; ++rnd) {
#pragma unroll
    for (int j = 0; j < 16; ++j) e[j] = cur[SIDX(t * 16 + j)];
    uint32_t cnt[4] = {0u, 0u, 0u, 0u};
#pragma unroll
    for (int j = 0; j < 16; ++j) {
      uint32_t d2 = (uint32_t)(e[j] >> (32 + 8 * P + 2 * rnd)) & 3u;
      cnt[d2]++;
    }
    uint32_t p0 = cnt[0] | (cnt[1] << 16);
    uint32_t p1 = cnt[2] | (cnt[3] << 16);
    uint32_t ex0, ex1, tot0, tot1;
    scan_pack2(p0, p1, scanS, ex0, ex1, tot0, tot1);
    uint32_t t0 = tot0 & 0xffffu, t1 = tot0 >> 16, t2 = tot1 & 0xffffu;
    uint32_t pos[4];
    pos[0] = (ex0 & 0xffffu);
    pos[1] = t0 + (ex0 >> 16);
    pos[2] = t0 + t1 + (ex1 & 0xffffu);
    pos[3] = t0 + t1 + t2 + (ex1 >> 16);
#pragma unroll
    for (int j = 0; j < 16; ++j) {
      uint32_t d2 = (uint32_t)(e[j] >> (32 + 8 * P + 2 * rnd)) & 3u;
      nxt[SIDX(pos[d2]++)] = e[j];
    }
    __syncthreads();
    uint64_t* tmp = cur; cur = nxt; nxt = tmp;
  }
  // cur == bufA: tile stably sorted by digit P

  // per-digit local starts + global bases
  ldsHist[t] = 0;
  __syncthreads();
#pragma unroll
  for (int j = 0; j < 16; ++j)
    atomicAdd(&ldsHist[(uint32_t)(e[j] >> (32 + 8 * P)) & 255u], 1u);
  ldsBase[t] = Hbk[(size_t)sl * HL + (size_t)t * NBLK + blk];
  __syncthreads();
  {
    uint32_t v = ldsHist[t];
    const int lane = t & 63, w = t >> 6;
    uint32_t s = v;
#pragma unroll
    for (int o = 1; o < 64; o <<= 1) {
      uint32_t n = __shfl_up(s, (unsigned)o, 64);
      if (lane >= o) s += n;
    }
    if (lane == 63) scanS[8 + w] = s;
    __syncthreads();
    if (t == 0) {
      uint32_t a = 0;
#pragma unroll
      for (int i = 0; i < 4; ++i) { uint32_t q = scanS[8 + i]; scanS[8 + i] = a; a += q; }
    }
    __syncthreads();
    ldsStart[t] = s - v + scanS[8 + w];
  }
  __syncthreads();

  // emit in sorted-tile order: digit runs -> contiguous global ranges
#pragma unroll
  for (int r = 0; r < 16; ++r) {
    uint32_t s = (uint32_t)(r * 256 + t);
    uint64_t el = cur[SIDX(s)];
    uint32_t d = (uint32_t)(el >> (32 + 8 * P)) & 255u;
    uint32_t dest = ldsBase[d] + s - ldsStart[d];
    if (MODE == 0) {
      dst[(size_t)sl * SEG_N + dest] = el;
    } else if (MODE == 1) {
      tsorted[dest] = finv((uint32_t)(el >> 32));
    } else {
      out[(size_t)(seg - 1) * SEG_N + (uint32_t)el] = tsorted[dest];
    }
  }
}

// ---------------------------------------------------------------------------
extern "C" void kernel_launch(void* const* d_in, const int* in_sizes, int n_in,
                              void* d_out, int out_size, void* d_ws, size_t ws_size,
                              hipStream_t stream) {
  const float* x = (const float*)d_in[0];
  const float* tmpl = (const float*)d_in[1];
  float* out = (float*)d_out;

  auto need = [](int nb) -> size_t {
    return (size_t)nb * ((size_t)SEG_N * 16 + (size_t)HL * 8 + 256) +
           (size_t)SEG_N * 4 + 8192;
  };
  const int nb = (ws_size >= need(9)) ? 9 : (ws_size >= need(3)) ? 3 : 1;

  uint8_t* w = (uint8_t*)d_ws;
  size_t off = 0;
  auto carve = [&](size_t bytes) -> void* {
    void* p = w + off;
    off = (off + bytes + 255) & ~(size_t)255;
    return p;
  };
  uint64_t* pairsA = (uint64_t*)carve((size_t)nb * SEG_N * 8);
  uint64_t* pairsB = (uint64_t*)carve((size_t)nb * SEG_N * 8);
  uint32_t* Hkb = (uint32_t*)carve((size_t)nb * HL * 4);
  uint32_t* Hbk = (uint32_t*)carve((size_t)nb * HL * 4);
  uint32_t* partials = (uint32_t*)carve((size_t)nb * 64 * 4);
  float* tsorted = (float*)carve((size_t)SEG_N * 4);

  for (int g = 0; g < NSEG; g += nb) {
    const dim3 gi(NBLK, nb);
    const dim3 gt(40, nb);
    const dim3 gs(SNB, nb);
    const dim3 g1(1, nb);

    auto scan_h = [&]() {
      transp_k<<<gt, 256, 0, stream>>>(Hkb, Hbk);
      scan_a_k<<<gs, 256, 0, stream>>>(Hbk, partials);
      scan_b_k<<<g1, 256, 0, stream>>>(partials);
      scan_c_k<<<gs, 256, 0, stream>>>(Hbk, partials);
    };

    // pass 0 (digit-0 hist fused into init)
    init_k<<<gi, 256, 0, stream>>>(x, tmpl, g, pairsA, Hkb);
    scan_h();
    part_k<0, 0><<<gi, 256, 0, stream>>>(pairsA, pairsB, Hbk, tsorted, out, g, 0);
    // pass 1
    hist_k<<<gi, 256, 0, stream>>>(pairsB, Hkb, 1);
    scan_h();
    part_k<1, 0><<<gi, 256, 0, stream>>>(pairsB, pairsA, Hbk, tsorted, out, g, 0);
    // pass 2
    hist_k<<<gi, 256, 0, stream>>>(pairsA, Hkb, 2);
    scan_h();
    part_k<2, 0><<<gi, 256, 0, stream>>>(pairsA, pairsB, Hbk, tsorted, out, g, 0);
    // pass 3 (fused epilogue)
    hist_k<<<gi, 256, 0, stream>>>(pairsB, Hkb, 3);
    scan_h();
    if (g == 0) {
      part_k<3, 1><<<dim3(NBLK, 1), 256, 0, stream>>>(pairsB, pairsA, Hbk,
                                                      tsorted, out, g, 0);
      if (nb > 1)
        part_k<3, 2><<<dim3(NBLK, nb - 1), 256, 0, stream>>>(pairsB, pairsA, Hbk,
                                                             tsorted, out, g, 1);
    } else {
      part_k<3, 2><<<dim3(NBLK, nb), 256, 0, stream>>>(pairsB, pairsA, Hbk,
                                                       tsorted, out, g, 0);
    }
  }
}